// Round 15
// baseline (103.150 us; speedup 1.0000x reference)
//
#include <hip/hip_runtime.h>
#include <math.h>

#define HGT 256
#define WID 256
#define NF 256
#define NP 160
#define SIGMAINV 7000.0f
#define EPSF 1e-10f
#define TW 1024
#define TH 1024
#define CHUNKS 8
#define FPC 32          // faces per chunk
#define PPB 128         // pixels per block (16x8 tile)
#define NTHR 512
#define CUT2 3.29e-3f   // 23.03 / SIGMAINV: beyond this d2, factor == 1 within 1e-10

// Opaque f32 ops the optimizer cannot re-contract or commute. Pins the EXACT
// contraction pattern of the reference (LLVM canonical: a*b - c*d ==>
// t = round(c*d); fma(a,b,-t)) so residual-noise normals on degenerate faces
// match the harness reference bitwise. DO NOT TOUCH — verified passing (r7-r14).
__device__ __forceinline__ float mul_opaque(float a, float b)
{
    float r;
    asm volatile("v_mul_f32 %0, %1, %2" : "=v"(r) : "v"(a), "v"(b));
    return r;
}
__device__ __forceinline__ float fma_opaque(float a, float b, float c)
{
    float r;
    asm volatile("v_fma_f32 %0, %1, %2, %3" : "=v"(r) : "v"(a), "v"(b), "v"(c));
    return r;
}

// Fused single kernel. 512 threads: slot = t>>3 (64 slots), chunk = t&7.
// Each slot owns 2 vertically-adjacent pixels; each (slot,chunk) thread scans
// 32 faces. Cross-chunk combine via 8-lane __shfl_xor butterfly (no LDS).
// improb accumulated as a PRODUCT of per-face factors (== exp of the ref's
// log-sum; same under/overflow regimes; error ~2e-6 << 2e-2 threshold).
// Face data staged as 5 float4 LDS words, bbox word first:
//   q0 = {bminx, bminy, bmaxx, bmaxy}   (bminx=+1e30 when face invalid)
//   q1 = {x0, y0, x1, y1}
//   q2 = {x2, y2, invA, z0}
//   q3 = {z1, z2, 0, 0}
//   q4 = {inv_ee0, inv_ee1, inv_ee2, 0}
__global__ __launch_bounds__(NTHR) void render_fused(
    const float* __restrict__ pts,     // 160*3
    const int*   __restrict__ faces,   // 256*3
    const float* __restrict__ rot,     // 3x3
    const float* __restrict__ cpos,    // 3
    const float* __restrict__ proj,    // 3
    const float* __restrict__ uvs,     // 160*2
    const int*   __restrict__ ft,      // 256*3
    const float* __restrict__ tex,     // 3 x 1024 x 1024 planar
    float*       __restrict__ out)     // imrender | improb | normal1
{
    __shared__ float4 sgeo4[NF * 5];   // 20 KB
    __shared__ float  scratch[800];    // prep only: sp[480] + sxy[320]

    float* sp  = scratch;
    float* sxy = scratch + 480;

    const int t = threadIdx.x;

    // ---- prep phase ----
    const float r00 = rot[0], r01 = rot[1], r02 = rot[2];
    const float r10 = rot[3], r11 = rot[4], r12 = rot[5];
    const float r20 = rot[6], r21 = rot[7], r22 = rot[8];
    const float cx = cpos[0], cy = cpos[1], cz = cpos[2];
    const float p0 = proj[0], p1 = proj[1], p2 = proj[2];

    if (t < NP) {
        float ax = pts[t * 3 + 0] - cx;
        float ay = pts[t * 3 + 1] - cy;
        float az = pts[t * 3 + 2] - cz;
        float qx = r00 * ax + r01 * ay + r02 * az;
        float qy = r10 * ax + r11 * ay + r12 * az;
        float qz = r20 * ax + r21 * ay + r22 * az;
        sp[t * 3 + 0] = qx; sp[t * 3 + 1] = qy; sp[t * 3 + 2] = qz;
        float zz = qz * p2;
        sxy[t * 2 + 0] = (qx * p0) / zz;
        sxy[t * 2 + 1] = (qy * p1) / zz;
    }
    __syncthreads();

    if (t < NF) {
        int i0 = faces[t * 3 + 0], i1 = faces[t * 3 + 1], i2 = faces[t * 3 + 2];
        float ax = sp[i0 * 3 + 0], ay = sp[i0 * 3 + 1], az = sp[i0 * 3 + 2];
        float bx = sp[i1 * 3 + 0], by = sp[i1 * 3 + 1], bz = sp[i1 * 3 + 2];
        float gx = sp[i2 * 3 + 0], gy = sp[i2 * 3 + 1], gz = sp[i2 * 3 + 2];

        // normal: ref's FMA-contracted f32 cross (r7-verified bit pattern)
        float e1x = bx - ax, e1y = by - ay, e1z = bz - az;
        float e2x = gx - ax, e2y = gy - ay, e2z = gz - az;
        float tnx = mul_opaque(e1z, e2y);
        float nx  = fma_opaque(e1y, e2z, -tnx);
        float tny = mul_opaque(e1x, e2z);
        float ny  = fma_opaque(e1z, e2x, -tny);
        float tnz = mul_opaque(e1y, e2x);
        float nz  = fma_opaque(e1x, e2y, -tnz);
        if (blockIdx.x == 0) {
            float s  = (mul_opaque(nx, nx) + mul_opaque(ny, ny)) + mul_opaque(nz, nz);
            float nl = sqrtf(s) + 1e-10f;
            float* out_normal = out + HGT * WID * 3 + HGT * WID;
            out_normal[t * 3 + 0] = nx / nl;
            out_normal[t * 3 + 1] = ny / nl;
            out_normal[t * 3 + 2] = nz / nl;
        }

        float x0 = sxy[i0 * 2 + 0], y0 = sxy[i0 * 2 + 1];
        float x1 = sxy[i1 * 2 + 0], y1 = sxy[i1 * 2 + 1];
        float x2 = sxy[i2 * 2 + 0], y2 = sxy[i2 * 2 + 1];
        float A = mul_opaque(x1 - x0, y2 - y0) - mul_opaque(x2 - x0, y1 - y0);
        bool okA = fabsf(A) > EPSF;
        bool valid = okA && (nz > 0.0f);
        float invA = okA ? 1.0f / A : 0.0f;

        float4 q0;
        if (valid) {
            q0.x = fminf(fminf(x0, x1), x2);
            q0.y = fminf(fminf(y0, y1), y2);
            q0.z = fmaxf(fmaxf(x0, x1), x2);
            q0.w = fmaxf(fmaxf(y0, y1), y2);
        } else {
            q0.x = 1e30f; q0.y = 1e30f; q0.z = -1e30f; q0.w = -1e30f;
        }
        float e0xp = x1 - x0, e0yp = y1 - y0;
        float e1xp = x2 - x1, e1yp = y2 - y1;
        float e2xp = x0 - x2, e2yp = y0 - y2;
        float iee0 = 1.0f / (e0xp * e0xp + e0yp * e0yp + EPSF);
        float iee1 = 1.0f / (e1xp * e1xp + e1yp * e1yp + EPSF);
        float iee2 = 1.0f / (e2xp * e2xp + e2yp * e2yp + EPSF);

        sgeo4[t * 5 + 0] = q0;
        sgeo4[t * 5 + 1] = make_float4(x0, y0, x1, y1);
        sgeo4[t * 5 + 2] = make_float4(x2, y2, invA, az);
        sgeo4[t * 5 + 3] = make_float4(bz, gz, 0.0f, 0.0f);
        sgeo4[t * 5 + 4] = make_float4(iee0, iee1, iee2, 0.0f);
    }
    __syncthreads();

    // ---- raster: slot owns 2 vertical pixels; chunk in lane bits 0..2 ----
    const int s = t >> 3;          // 0..63
    const int c = t & 7;           // chunk
    const int tx = (blockIdx.x & 15) * 16;  // 16 tiles across
    const int ty = (blockIdx.x >> 4) * 8;   // 32 tiles down
    const int w  = tx + (s & 15);
    const int h0 = ty + 2 * (s >> 4);
    const int h1 = h0 + 1;
    const float px  = ((float)w + 0.5f) / (float)WID * 2.0f - 1.0f;
    const float py0 = 1.0f - ((float)h0 + 0.5f) / (float)HGT * 2.0f;
    const float py1 = 1.0f - ((float)h1 + 0.5f) / (float)HGT * 2.0f;

    float bz0 = -1e30f, bz1 = -1e30f;
    int   bf0 = 0,      bf1 = 0;
    float pr0 = 1.0f,   pr1 = 1.0f;

    const int f0 = c * FPC;
    for (int f = f0; f < f0 + FPC; ++f) {
        float4 q0 = sgeo4[f * 5 + 0];
        float ddx  = fmaxf(fmaxf(q0.x - px, px - q0.z), 0.0f);   // shared column
        float ddy0 = fmaxf(fmaxf(q0.y - py0, py0 - q0.w), 0.0f);
        float ddy1 = fmaxf(fmaxf(q0.y - py1, py1 - q0.w), 0.0f);
        float bd0 = ddx * ddx + ddy0 * ddy0;
        float bd1 = ddx * ddx + ddy1 * ddy1;
        if (fminf(bd0, bd1) > CUT2) continue;   // both pixels negligible

        float4 q1 = sgeo4[f * 5 + 1];
        float4 q2 = sgeo4[f * 5 + 2];
        float4 q3 = sgeo4[f * 5 + 3];
        float4 q4 = sgeo4[f * 5 + 4];

        #pragma unroll
        for (int k = 0; k < 2; ++k) {
            float py = k ? py1 : py0;
            float ax = q1.z - px, ay = q1.w - py;   // v1 - p
            float bx = q2.x - px, by = q2.y - py;   // v2 - p
            float gx = q1.x - px, gy = q1.y - py;   // v0 - p
            float w0 = (ax * by - bx * ay) * q2.z;
            float w1 = (bx * gy - gx * by) * q2.z;
            float w2 = 1.0f - w0 - w1;
            bool inside = (w0 >= 0.0f) & (w1 >= 0.0f) & (w2 >= 0.0f);
            float z = w0 * q2.w + w1 * q3.x + w2 * q3.y;

            // single-edge selection (exact; see r14): w0<0 -> edge v1v2,
            // else w1<0 -> edge v2v0, else edge v0v1 (garbage when inside,
            // overridden by select below)
            bool s0 = (w0 < 0.0f);
            bool s1 = (w1 < 0.0f);
            float Sx  = s0 ? ax   : (s1 ? bx   : gx);
            float Sy  = s0 ? ay   : (s1 ? by   : gy);
            float Tx  = s0 ? bx   : (s1 ? gx   : ax);
            float Ty  = s0 ? by   : (s1 ? gy   : ay);
            float iee = s0 ? q4.y : (s1 ? q4.z : q4.x);
            float Ex = Tx - Sx, Ey = Ty - Sy;
            float tt = fminf(fmaxf(-(Sx * Ex + Sy * Ey) * iee, 0.0f), 1.0f);
            float dx = fmaf(tt, Ex, Sx), dy = fmaf(tt, Ey, Sy);
            float d2 = dx * dx + dy * dy;
            float a = d2 * SIGMAINV;
            float fct = fmaxf(1.0f - __expf(-a), 1e-10f);
            fct = (a < 23.03f) ? fct : 1.0f;
            fct = inside ? 1e-10f : fct;

            if (k == 0) {
                if (inside && z > bz0) { bz0 = z; bf0 = f; }
                pr0 *= fct;
            } else {
                if (inside && z > bz1) { bz1 = z; bf1 = f; }
                pr1 *= fct;
            }
        }
    }

    // ---- cross-chunk butterfly over lane bits 0..2 ----
    #pragma unroll
    for (int m = 1; m <= 4; m <<= 1) {
        float oz0 = __shfl_xor(bz0, m); int of0 = __shfl_xor(bf0, m);
        float op0 = __shfl_xor(pr0, m);
        float oz1 = __shfl_xor(bz1, m); int of1 = __shfl_xor(bf1, m);
        float op1 = __shfl_xor(pr1, m);
        if (oz0 > bz0 || (oz0 == bz0 && of0 < bf0)) { bz0 = oz0; bf0 = of0; }
        if (oz1 > bz1 || (oz1 == bz1 && of1 < bf1)) { bz1 = oz1; bf1 = of1; }
        pr0 *= op0;
        pr1 *= op1;
    }

    if (c == 0) {
        #pragma unroll
        for (int k = 0; k < 2; ++k) {
            int   h   = k ? h1  : h0;
            float py  = k ? py1 : py0;
            float bz  = k ? bz1 : bz0;
            int   bf  = k ? bf1 : bf0;
            float pr  = k ? pr1 : pr0;
            const int pix = h * WID + w;
            out[HGT * WID * 3 + pix] = 1.0f - pr;

            float cr = 0.0f, cg = 0.0f, cb = 0.0f;
            if (bz > -1e29f) {
                float4 q1 = sgeo4[bf * 5 + 1];
                float4 q2 = sgeo4[bf * 5 + 2];
                float axx = q1.z - px, ayy = q1.w - py;
                float bxx = q2.x - px, byy = q2.y - py;
                float gxx = q1.x - px, gyy = q1.y - py;
                float w0 = (axx * byy - bxx * ayy) * q2.z;
                float w1 = (bxx * gyy - gxx * byy) * q2.z;
                float w2 = 1.0f - w0 - w1;
                int j0 = ft[bf * 3 + 0], j1 = ft[bf * 3 + 1], j2 = ft[bf * 3 + 2];
                float u = w0 * uvs[j0 * 2 + 0] + w1 * uvs[j1 * 2 + 0] + w2 * uvs[j2 * 2 + 0];
                float v = w0 * uvs[j0 * 2 + 1] + w1 * uvs[j1 * 2 + 1] + w2 * uvs[j2 * 2 + 1];
                float mask = w0 + w1 + w2;

                float x = u * (float)(TW - 1);
                float y = (1.0f - v) * (float)(TH - 1);
                float x0f = fminf(fmaxf(floorf(x), 0.0f), (float)(TW - 1));
                float y0f = fminf(fmaxf(floorf(y), 0.0f), (float)(TH - 1));
                int xi0 = (int)x0f, yi0 = (int)y0f;
                int xi1 = min(xi0 + 1, TW - 1);
                int yi1 = min(yi0 + 1, TH - 1);
                float wx = fminf(fmaxf(x - x0f, 0.0f), 1.0f);
                float wy = fminf(fmaxf(y - y0f, 0.0f), 1.0f);

                int o00 = yi0 * TW + xi0, o01 = yi0 * TW + xi1;
                int o10 = yi1 * TW + xi0, o11 = yi1 * TW + xi1;
                #pragma unroll
                for (int ch = 0; ch < 3; ++ch) {
                    const float* tp = tex + ch * (TW * TH);
                    float c00 = tp[o00], c01 = tp[o01], c10 = tp[o10], c11 = tp[o11];
                    float col = (c00 * (1.0f - wx) + c01 * wx) * (1.0f - wy)
                              + (c10 * (1.0f - wx) + c11 * wx) * wy;
                    col = fminf(fmaxf(col * mask, 0.0f), 1.0f);
                    if (ch == 0) cr = col; else if (ch == 1) cg = col; else cb = col;
                }
            }
            out[pix * 3 + 0] = cr;
            out[pix * 3 + 1] = cg;
            out[pix * 3 + 2] = cb;
        }
    }
}

extern "C" void kernel_launch(void* const* d_in, const int* in_sizes, int n_in,
                              void* d_out, int out_size, void* d_ws, size_t ws_size,
                              hipStream_t stream)
{
    const float* pts   = (const float*)d_in[0];
    const int*   faces = (const int*)  d_in[1];
    const float* rot   = (const float*)d_in[2];
    const float* cpos  = (const float*)d_in[3];
    const float* proj  = (const float*)d_in[4];
    const float* uvs   = (const float*)d_in[5];
    const int*   ft    = (const int*)  d_in[6];
    const float* tex   = (const float*)d_in[7];
    float* out = (float*)d_out;

    render_fused<<<(HGT * WID) / PPB, NTHR, 0, stream>>>(
        pts, faces, rot, cpos, proj, uvs, ft, tex, out);
}